// Round 4
// baseline (386.387 us; speedup 1.0000x reference)
//
#include <hip/hip_runtime.h>
#include <hip/hip_bf16.h>

// Llama4 Vision Attention, MI355X bf16-MFMA pipeline.
// B=16 S=576 E=1408 H=16 D=88 (pad 96). fp32 in/out, bf16 internal compute.

typedef unsigned short UST;
typedef __attribute__((ext_vector_type(8))) __bf16 bf16x8;
typedef __attribute__((ext_vector_type(4))) float f32x4;
typedef __attribute__((ext_vector_type(8))) UST us8;
typedef __attribute__((ext_vector_type(4))) UST us4;

typedef __attribute__((address_space(3))) unsigned int lds_u32;
typedef const __attribute__((address_space(1))) unsigned int glob_u32;

static __device__ __forceinline__ float bf2f(UST u){
  unsigned int x = ((unsigned int)u) << 16;
  return __builtin_bit_cast(float, x);
}
static __device__ __forceinline__ UST f2bf(float f){
  unsigned int x = __builtin_bit_cast(unsigned int, f);
  x += 0x7fffu + ((x >> 16) & 1u);   // RN-even; inputs finite
  return (UST)(x >> 16);
}

// ---------------- RoPE tables: cos/sin [576][44], f64 math to match numpy ----
__global__ void k_tables(float* __restrict__ cosT, float* __restrict__ sinT){
  int s = blockIdx.x;
  int p = threadIdx.x;
  if (p >= 44) return;
  int tt = p % 22;
  double comp = (p < 22) ? (double)(s % 24 + 1) : (double)(s / 24 + 1);
  double a = comp * pow(10000.0, -(double)tt / 22.0);
  cosT[s*44 + p] = (float)cos(a);
  sinT[s*44 + p] = (float)sin(a);
}

// ---------------- fp32 -> bf16 cast (vectorized) ----------------------------
__global__ void k_cvt(const float* __restrict__ in, UST* __restrict__ out, int n4){
  int i = blockIdx.x * 256 + threadIdx.x;
  if (i >= n4) return;
  float4 v = ((const float4*)in)[i];
  us4 o; o[0]=f2bf(v.x); o[1]=f2bf(v.y); o[2]=f2bf(v.z); o[3]=f2bf(v.w);
  *(us4*)(out + 4*(size_t)i) = o;
}

// ---------------- fp32 [K][N] -> bf16 [N][K] transpose-convert --------------
__global__ void k_cvt_t(const float* __restrict__ W, UST* __restrict__ Bt, int K, int N){
  __shared__ __align__(16) UST tl[64][70];  // odd dword stride -> low conflict
  int kt = blockIdx.x, nt = blockIdx.y;
  int t = threadIdx.x;
  int k = t >> 2, u = t & 3;
  const float* src = W + (size_t)(kt*64 + k)*N + nt*64 + u*16;
#pragma unroll
  for (int i = 0; i < 4; ++i){
    float4 v = *(const float4*)(src + 4*i);
    UST* d = &tl[k][u*16 + 4*i];
    d[0]=f2bf(v.x); d[1]=f2bf(v.y); d[2]=f2bf(v.z); d[3]=f2bf(v.w);
  }
  __syncthreads();
  int n = t >> 2;
  UST* dst = Bt + (size_t)(nt*64 + n)*K + kt*64 + u*16;
#pragma unroll
  for (int i = 0; i < 2; ++i){
    us8 o;
#pragma unroll
    for (int j = 0; j < 8; ++j) o[j] = tl[u*16 + 8*i + j][n];
    *(us8*)(dst + 8*i) = o;
  }
}

// ---------------- bf16 GEMM: C[M][N] = A[M][K] @ Bt[N][K]^T + bias ----------
// Round-2 proven body (128x128, BK=64, 2 blocks/CU) + counted vmcnt(8) with
// raw s_barrier pair (no full drain) + bijective XCD swizzle (1D grid, nwg%8==0).
template<bool OUT_BF16>
__global__ __launch_bounds__(256, 2) void k_gemm(
    const UST* __restrict__ A, const UST* __restrict__ Bt,
    const float* __restrict__ bias, void* __restrict__ Cout,
    int M, int N, int K)
{
  __shared__ __align__(16) UST lA[2][128][64];
  __shared__ __align__(16) UST lB[2][128][64];
  const int t = threadIdx.x;
  // XCD swizzle: consecutive v share bn (B-panel stays in one XCD's L2)
  const int nwg = gridDim.x;
  const int v = (blockIdx.x & 7) * (nwg >> 3) + (blockIdx.x >> 3);
  const int mb = M >> 7;
  const int bm = v % mb, bn = v / mb;
  const int wave = t >> 6, lane = t & 63;
  const int lm = lane & 15, g = lane >> 4;
  const int wr = (wave >> 1) << 6, wc = (wave & 1) << 6;
  const int lrow = lane >> 3;                       // 0..7 within 8-row chunk
  const int lcol = (((lane & 7) ^ lrow) << 3);      // pre-swizzled source col
  const UST* Ag = A  + (size_t)(bm*128 + wave*32 + lrow)*K + lcol;
  const UST* Bg = Bt + (size_t)(bn*128 + wave*32 + lrow)*K + lcol;

  f32x4 zero = {0.f,0.f,0.f,0.f};
  f32x4 acc[4][4];
#pragma unroll
  for (int i=0;i<4;++i)
#pragma unroll
    for (int j=0;j<4;++j) acc[i][j] = zero;

  const int nkt = K >> 6;
  auto stage = [&](int kt, int buf){           // 8 global_load_lds per thread
#pragma unroll
    for (int c = 0; c < 4; ++c){
      __builtin_amdgcn_global_load_lds((glob_u32*)(Ag + (size_t)kt*64 + (size_t)(8*c)*K),
                                       (lds_u32*)(&lA[buf][wave*32 + 8*c][0]), 16, 0, 0);
      __builtin_amdgcn_global_load_lds((glob_u32*)(Bg + (size_t)kt*64 + (size_t)(8*c)*K),
                                       (lds_u32*)(&lB[buf][wave*32 + 8*c][0]), 16, 0, 0);
    }
  };

  stage(0, 0);
  const int swz = (lm & 7) << 3;

  for (int kt = 0; kt < nkt; ++kt){
    const int cur = kt & 1;
    stage((kt + 1) % nkt, cur ^ 1);            // wrap keeps vmcnt FIFO count exact
    asm volatile("s_waitcnt vmcnt(8)" ::: "memory");  // retire cur's 8, keep new 8 in flight
    __builtin_amdgcn_sched_barrier(0);
    __builtin_amdgcn_s_barrier();              // all waves' cur loads landed
#pragma unroll
    for (int ks = 0; ks < 2; ++ks){
      bf16x8 af[4], bfv[4];
      const int cb = (ks*32 + g*8) ^ swz;
#pragma unroll
      for (int mf = 0; mf < 4; ++mf)
        af[mf] = __builtin_bit_cast(bf16x8, *(const us8*)&lA[cur][wr + mf*16 + lm][cb]);
#pragma unroll
      for (int nf = 0; nf < 4; ++nf)
        bfv[nf] = __builtin_bit_cast(bf16x8, *(const us8*)&lB[cur][wc + nf*16 + lm][cb]);
#pragma unroll
      for (int mf = 0; mf < 4; ++mf)
#pragma unroll
        for (int nf = 0; nf < 4; ++nf)
          acc[mf][nf] = __builtin_amdgcn_mfma_f32_16x16x32_bf16(af[mf], bfv[nf], acc[mf][nf], 0, 0, 0);
    }
    __builtin_amdgcn_s_barrier();              // reads of cur retired before overwrite
  }

#pragma unroll
  for (int nf = 0; nf < 4; ++nf){
    const int col = bn*128 + wc + nf*16 + lm;
    const float bv = bias[col];
#pragma unroll
    for (int mf = 0; mf < 4; ++mf){
      const size_t rb = (size_t)(bm*128 + wr + mf*16 + g*4);
#pragma unroll
      for (int r = 0; r < 4; ++r){
        float v2 = acc[mf][nf][r] + bv;
        if (OUT_BF16) ((UST*)Cout)[(rb + r)*(size_t)N + col] = f2bf(v2);
        else          ((float*)Cout)[(rb + r)*(size_t)N + col] = v2;
      }
    }
  }
}

// ---------------- RoPE + pack: qkv[9216][4224] -> qa/ka [bh][s][96], vt [bh][96][576]
__global__ __launch_bounds__(256) void k_rope(
    const UST* __restrict__ qkv, const float* __restrict__ cosT, const float* __restrict__ sinT,
    UST* __restrict__ qa, UST* __restrict__ ka, UST* __restrict__ vt)
{
  __shared__ float lc[64][44], lsn[64][44];
  __shared__ __align__(16) UST sl[64][104];
  const int bh = blockIdx.x, st = blockIdx.y;
  const int b = bh >> 4, h = bh & 15;
  const int t = threadIdx.x;
  const int s0 = st * 64;
  for (int c = t; c < 64*44; c += 256){
    int s = c / 44, p = c % 44;
    lc[s][p]  = cosT[(s0+s)*44 + p];
    lsn[s][p] = sinT[(s0+s)*44 + p];
  }
  const size_t rowbase = ((size_t)(b*576 + s0))*4224 + h*88;

  for (int j = 0; j < 2; ++j){
    __syncthreads();
    for (int c = t; c < 704; c += 256){
      int r = c / 11, ch = c % 11;
      int chS = (ch < 8) ? (ch ^ ((r>>3)&7)) : ch;
      *(uint4*)&sl[r][chS*8] = *(const uint4*)(qkv + rowbase + (size_t)r*4224 + j*1408 + ch*8);
    }
    __syncthreads();
    const int s = t >> 2, u = t & 3;
    const size_t obase = ((size_t)bh*576 + s0 + s)*96;
    UST* outp = (j == 0) ? qa : ka;
    const float sc = (j == 0) ? 0.10660035817780521f : 1.0f;  // 88^-0.5 folded into q
    const int sw3 = (s>>3)&7;
#pragma unroll
    for (int i = 0; i < 11; ++i){
      int p = u*11 + i;
      int e = 2*p;
      int chunk = e >> 3;
      int pos = ((chunk < 8) ? (chunk ^ sw3) : chunk)*8 + (e & 7);
      float x0 = bf2f(sl[s][pos]);
      float x1 = bf2f(sl[s][pos+1]);
      float cv = lc[s][p], sv = lsn[s][p];
      float o0 = (x0*cv - x1*sv)*sc;
      float o1 = (x0*sv + x1*cv)*sc;
      unsigned int pk = (unsigned int)f2bf(o0) | ((unsigned int)f2bf(o1) << 16);
      *(unsigned int*)(outp + obase + 2*p) = pk;
    }
    if (u == 3){ uint4 z = {0,0,0,0}; *(uint4*)(outp + obase + 88) = z; }
  }

  __syncthreads();
  for (int c = t; c < 704; c += 256){
    int r = c / 11, ch = c % 11;
    int chS = (ch < 8) ? (ch ^ ((r>>3)&7)) : ch;
    *(uint4*)&sl[r][chS*8] = *(const uint4*)(qkv + rowbase + (size_t)r*4224 + 2*1408 + ch*8);
  }
  __syncthreads();
  for (int c = t; c < 768; c += 256){
    int d = c >> 3, ch = c & 7;
    us8 o;
    if (d < 88){
      int chunk = d >> 3;
#pragma unroll
      for (int jj = 0; jj < 8; ++jj){
        int r = ch*8 + jj;
        int pos = ((chunk < 8) ? (chunk ^ (ch & 7)) : chunk)*8 + (d & 7);
        o[jj] = sl[r][pos];
      }
    } else {
#pragma unroll
      for (int jj = 0; jj < 8; ++jj) o[jj] = 0;
    }
    *(us8*)(vt + ((size_t)bh*96 + d)*576 + s0 + ch*8) = o;
  }
}

// ---------------- flash attention: dbuf async K/V staging, counted vmcnt ----
// Grid 1D 2304, XCD-swizzled so the 9 q-tiles of one (b,h) share an XCD's L2.
// K/V staged via global_load_lds with chunk-XOR swizzle (both-sides involution):
//   lK[64][96]: chunks 0-7 ^ (row&7), chunks 8-11: 8 + ((c-8)^(row&3))
//   lV[96][64]: chunks 0-7 ^ (row&7)
__global__ __launch_bounds__(256, 2) void k_attn(
    const UST* __restrict__ qa, const UST* __restrict__ ka,
    const UST* __restrict__ vt, UST* __restrict__ outp)
{
  __shared__ __align__(16) UST lK[2][64][96];   // 2 x 12KB
  __shared__ __align__(16) UST lV[2][96][64];   // 2 x 12KB
  __shared__ __align__(16) UST lP[4][16][72];   // per-wave P [q][kv]
  const int nwg = gridDim.x;
  const int vswz = (blockIdx.x & 7) * (nwg >> 3) + (blockIdx.x >> 3);
  const int qt = vswz % 9, bh = vswz / 9;
  const int t = threadIdx.x, wave = t >> 6, lane = t & 63;
  const int lm = lane & 15, g = lane >> 4;
  const int h = bh & 15, b = bh >> 4;

  const UST* kbase = ka + (size_t)bh*576*96;
  const UST* vbase = vt + (size_t)bh*96*576;

  // staging address precompute (3 K-instrs + 3 V-instrs per thread, 16B each)
  int koff[3], vofs[3], ldsoff[3];
#pragma unroll
  for (int i = 0; i < 3; ++i){
    int ch = (i*4 + wave)*64 + lane;          // 16B chunk id, 0..767
    int rK = ch / 12, pcK = ch % 12;
    int scK = (pcK < 8) ? (pcK ^ (rK & 7)) : (8 + ((pcK - 8) ^ (rK & 3)));
    koff[i] = rK*96 + scK*8;
    int rV = ch >> 3, pcV = ch & 7;
    vofs[i] = rV*576 + (pcV ^ (rV & 7))*8;
    ldsoff[i] = (i*4 + wave)*512;             // UST units
  }
  auto stage = [&](int kvt, int buf){         // 6 global_load_lds per thread
#pragma unroll
    for (int i = 0; i < 3; ++i){
      __builtin_amdgcn_global_load_lds((glob_u32*)(kbase + (size_t)kvt*6144 + koff[i]),
                                       (lds_u32*)((UST*)&lK[buf][0][0] + ldsoff[i]), 16, 0, 0);
      __builtin_amdgcn_global_load_lds((glob_u32*)(vbase + (size_t)kvt*64 + vofs[i]),
                                       (lds_u32*)((UST*)&lV[buf][0][0] + ldsoff[i]), 16, 0, 0);
    }
  };

  bf16x8 qf[3];
  {
    const UST* qp = qa + ((size_t)bh*576 + qt*64 + wave*16 + lm)*96 + g*8;
#pragma unroll
    for (int ks = 0; ks < 3; ++ks) qf[ks] = __builtin_bit_cast(bf16x8, *(const us8*)(qp + ks*32));
  }
  f32x4 zero = {0.f,0.f,0.f,0.f};
  f32x4 acc[6];
#pragma unroll
  for (int i = 0; i < 6; ++i) acc[i] = zero;
  float mrun[4], lrun[4];
#pragma unroll
  for (int r = 0; r < 4; ++r){ mrun[r] = -1e30f; lrun[r] = 0.f; }

  // read-side swizzled column offsets (involution with stage side)
  int kcol_r[3], vcol_r[2];
  kcol_r[0] = ((0*4 + g) ^ (lm & 7)) * 8;
  kcol_r[1] = ((1*4 + g) ^ (lm & 7)) * 8;
  kcol_r[2] = (8 + (g ^ (lm & 3))) * 8;
#pragma unroll
  for (int ks2 = 0; ks2 < 2; ++ks2) vcol_r[ks2] = ((ks2*4 + g) ^ (lm & 7)) * 8;

  stage(0, 0);

  for (int kvt = 0; kvt < 9; ++kvt){
    const int cur = kvt & 1;
    stage((kvt + 1) % 9, cur ^ 1);            // wrap keeps FIFO count exact
    asm volatile("s_waitcnt vmcnt(6)" ::: "memory");  // cur's 6 landed, new 6 in flight
    __builtin_amdgcn_sched_barrier(0);
    __builtin_amdgcn_s_barrier();

    // QK^T -> sc[nf][r]: S[q = wave*16 + 4g+r][kv = nf*16 + lm]
    f32x4 sc[4];
#pragma unroll
    for (int i = 0; i < 4; ++i) sc[i] = zero;
    __builtin_amdgcn_s_setprio(1);
#pragma unroll
    for (int ks = 0; ks < 3; ++ks){
#pragma unroll
      for (int nf = 0; nf < 4; ++nf){
        bf16x8 kf = __builtin_bit_cast(bf16x8, *(const us8*)&lK[cur][nf*16 + lm][kcol_r[ks]]);
        sc[nf] = __builtin_amdgcn_mfma_f32_16x16x32_bf16(qf[ks], kf, sc[nf], 0, 0, 0);
      }
    }
    __builtin_amdgcn_s_setprio(0);

    // online softmax
    float mx[4];
#pragma unroll
    for (int r = 0; r < 4; ++r)
      mx[r] = fmaxf(fmaxf(sc[0][r], sc[1][r]), fmaxf(sc[2][r], sc[3][r]));
#pragma unroll
    for (int m = 1; m <= 8; m <<= 1)
#pragma unroll
      for (int r = 0; r < 4; ++r) mx[r] = fmaxf(mx[r], __shfl_xor(mx[r], m, 64));
    float al[4];
#pragma unroll
    for (int r = 0; r < 4; ++r){
      float mnew = fmaxf(mrun[r], mx[r]);
      float corr = __expf(mrun[r] - mnew);
      mrun[r] = mnew;
      lrun[r] *= corr;
      float ls = 0.f;
#pragma unroll
      for (int nf = 0; nf < 4; ++nf){
        float p = __expf(sc[nf][r] - mnew);
        sc[nf][r] = p;
        ls += p;
      }
#pragma unroll
      for (int df = 0; df < 6; ++df) acc[df][r] *= corr;
      al[r] = ls;
    }
#pragma unroll
    for (int m = 1; m <= 8; m <<= 1)
#pragma unroll
      for (int r = 0; r < 4; ++r) al[r] += __shfl_xor(al[r], m, 64);
#pragma unroll
    for (int r = 0; r < 4; ++r) lrun[r] += al[r];

    // P -> LDS (wave-local), read back as A-frags
#pragma unroll
    for (int nf = 0; nf < 4; ++nf)
#pragma unroll
      for (int r = 0; r < 4; ++r)
        lP[wave][4*g + r][nf*16 + lm] = f2bf(sc[nf][r]);

    bf16x8 pa[2];
#pragma unroll
    for (int ks2 = 0; ks2 < 2; ++ks2)
      pa[ks2] = __builtin_bit_cast(bf16x8, *(const us8*)&lP[wave][lm][ks2*32 + g*8]);
    __builtin_amdgcn_s_setprio(1);
#pragma unroll
    for (int ks2 = 0; ks2 < 2; ++ks2)
#pragma unroll
      for (int df = 0; df < 6; ++df){
        bf16x8 vf = __builtin_bit_cast(bf16x8, *(const us8*)&lV[cur][df*16 + lm][vcol_r[ks2]]);
        acc[df] = __builtin_amdgcn_mfma_f32_16x16x32_bf16(pa[ks2], vf, acc[df], 0, 0, 0);
      }
    __builtin_amdgcn_s_setprio(0);
    __builtin_amdgcn_s_barrier();             // reads of cur retired before overwrite
  }

  float inv[4];
#pragma unroll
  for (int r = 0; r < 4; ++r) inv[r] = 1.f / lrun[r];
  const size_t rowt = (size_t)b*576 + qt*64 + wave*16;
#pragma unroll
  for (int df = 0; df < 6; ++df){
    int d = df*16 + lm;
    if (d < 88){
#pragma unroll
      for (int r = 0; r < 4; ++r)
        outp[(rowt + 4*g + r)*1408 + h*88 + d] = f2bf(acc[df][r] * inv[r]);
    }
  }
}

// ---------------- launch ----------------------------------------------------
extern "C" void kernel_launch(void* const* d_in, const int* in_sizes, int n_in,
                              void* d_out, int out_size, void* d_ws, size_t ws_size,
                              hipStream_t stream)
{
  (void)in_sizes; (void)n_in; (void)out_size; (void)ws_size;
  const float* hs   = (const float*)d_in[0];
  const float* wqkv = (const float*)d_in[1];
  const float* bqkv = (const float*)d_in[2];
  const float* wo   = (const float*)d_in[3];
  const float* bo   = (const float*)d_in[4];
  float* out = (float*)d_out;

  char* w = (char*)d_ws;                       // needs ~195.3 MiB
  UST* A_bf   = (UST*)(w);                     // 25,952,256  (hidden bf16; reused as attn out)
  UST* Bt1    = (UST*)(w + 25952256);          // 11,894,784  (w_qkv^T bf16)
  UST* Bt2    = (UST*)(w + 37847040);          //  3,964,928  (w_o^T bf16)
  UST* qkvb   = (UST*)(w + 41811968);          // 77,856,768  (qkv bf16)
  UST* qa     = (UST*)(w + 119668736);         // 28,311,552
  UST* ka     = (UST*)(w + 147980288);         // 28,311,552
  UST* vt     = (UST*)(w + 176291840);         // 28,311,552
  float* cosT = (float*)(w + 204603392);       //    101,376
  float* sinT = (float*)(w + 204704768);       //    101,376

  k_tables<<<576, 64, 0, stream>>>(cosT, sinT);
  k_cvt<<<12672, 256, 0, stream>>>(hs, A_bf, 3244032);
  k_cvt_t<<<dim3(22, 66), 256, 0, stream>>>(wqkv, Bt1, 1408, 4224);
  k_cvt_t<<<dim3(22, 22), 256, 0, stream>>>(wo, Bt2, 1408, 1408);
  k_gemm<true ><<<2376, 256, 0, stream>>>(A_bf, Bt1, bqkv, qkvb, 9216, 4224, 1408);
  k_rope<<<dim3(256, 9), 256, 0, stream>>>(qkvb, cosT, sinT, qa, ka, vt);
  k_attn<<<2304, 256, 0, stream>>>(qa, ka, vt, A_bf);
  k_gemm<false><<<792, 256, 0, stream>>>(A_bf, Bt2, bo, out, 9216, 1408, 1408);
}

// Round 5
// 359.496 us; speedup vs baseline: 1.0748x; 1.0748x over previous
//
#include <hip/hip_runtime.h>
#include <hip/hip_bf16.h>

// Llama4 Vision Attention, MI355X bf16-MFMA pipeline.
// B=16 S=576 E=1408 H=16 D=88 (pad 96). fp32 in/out, bf16 internal compute.
// R5: rope pass fused away (V via GEMM epilogue transpose, Q/K via elementwise
//     in-register pair rope); GEMM/attn bodies = round-2 proven versions.

typedef unsigned short UST;
typedef __attribute__((ext_vector_type(8))) __bf16 bf16x8;
typedef __attribute__((ext_vector_type(4))) float f32x4;
typedef __attribute__((ext_vector_type(8))) UST us8;
typedef __attribute__((ext_vector_type(4))) UST us4;

typedef __attribute__((address_space(3))) unsigned int lds_u32;
typedef const __attribute__((address_space(1))) unsigned int glob_u32;

static __device__ __forceinline__ float bf2f(UST u){
  unsigned int x = ((unsigned int)u) << 16;
  return __builtin_bit_cast(float, x);
}
static __device__ __forceinline__ UST f2bf(float f){
  unsigned int x = __builtin_bit_cast(unsigned int, f);
  x += 0x7fffu + ((x >> 16) & 1u);   // RN-even; inputs finite
  return (UST)(x >> 16);
}

// ---------------- RoPE tables: interleaved {cos,sin}[576][44] (f64 math) ----
__global__ void k_tables(float* __restrict__ cs2){
  int s = blockIdx.x;
  int p = threadIdx.x;
  if (p >= 44) return;
  int tt = p % 22;
  double comp = (p < 22) ? (double)(s % 24 + 1) : (double)(s / 24 + 1);
  double a = comp * pow(10000.0, -(double)tt / 22.0);
  cs2[s*88 + 2*p]     = (float)cos(a);
  cs2[s*88 + 2*p + 1] = (float)sin(a);
}

// ---------------- zero vt pad rows d=88..95 ---------------------------------
__global__ void k_zero(UST* __restrict__ vt){
  int c = blockIdx.x*256 + threadIdx.x;        // 0..147455
  int bh = c / 576, w = c - bh*576;
  us8 z = {0,0,0,0,0,0,0,0};
  *(us8*)(vt + (size_t)bh*55296 + 50688 + w*8) = z;
}

// ---------------- fp32 -> bf16 cast (vectorized) ----------------------------
__global__ void k_cvt(const float* __restrict__ in, UST* __restrict__ out, int n4){
  int i = blockIdx.x * 256 + threadIdx.x;
  if (i >= n4) return;
  float4 v = ((const float4*)in)[i];
  us4 o; o[0]=f2bf(v.x); o[1]=f2bf(v.y); o[2]=f2bf(v.z); o[3]=f2bf(v.w);
  *(us4*)(out + 4*(size_t)i) = o;
}

// ---------------- fp32 [K][N] -> bf16 [N][K] transpose-convert --------------
__global__ void k_cvt_t(const float* __restrict__ W, UST* __restrict__ Bt, int K, int N){
  __shared__ __align__(16) UST tl[64][70];  // odd dword stride -> low conflict
  int kt = blockIdx.x, nt = blockIdx.y;
  int t = threadIdx.x;
  int k = t >> 2, u = t & 3;
  const float* src = W + (size_t)(kt*64 + k)*N + nt*64 + u*16;
#pragma unroll
  for (int i = 0; i < 4; ++i){
    float4 v = *(const float4*)(src + 4*i);
    UST* d = &tl[k][u*16 + 4*i];
    d[0]=f2bf(v.x); d[1]=f2bf(v.y); d[2]=f2bf(v.z); d[3]=f2bf(v.w);
  }
  __syncthreads();
  int n = t >> 2;
  UST* dst = Bt + (size_t)(nt*64 + n)*K + kt*64 + u*16;
#pragma unroll
  for (int i = 0; i < 2; ++i){
    us8 o;
#pragma unroll
    for (int j = 0; j < 8; ++j) o[j] = tl[u*16 + 8*i + j][n];
    *(us8*)(dst + 8*i) = o;
  }
}

// ---------------- bf16 GEMM (round-2 proven body) + fused epilogues ---------
// EPI 0: fp32 out, stride N. EPI 1: bf16 out, stride N (qkv q/k region).
// EPI 2: v-region -> vt[bh][96][576] transposed bf16 store (cols 2816+).
template<int EPI>
__global__ __launch_bounds__(256, 2) void k_gemm(
    const UST* __restrict__ A, const UST* __restrict__ Bt,
    const float* __restrict__ bias, void* __restrict__ Cout,
    int M, int N, int K, int bn0)
{
  __shared__ __align__(16) UST lA[2][128][64];
  __shared__ __align__(16) UST lB[2][128][64];
  const int t = threadIdx.x;
  const int bm = blockIdx.x, bn = blockIdx.y + bn0;
  const int wave = t >> 6, lane = t & 63;
  const int lm = lane & 15, g = lane >> 4;
  const int wr = (wave >> 1) << 6, wc = (wave & 1) << 6;
  const int lrow = lane >> 3;                       // 0..7 within 8-row chunk
  const int lcol = (((lane & 7) ^ lrow) << 3);      // pre-swizzled source col
  const UST* Ag = A  + (size_t)(bm*128 + wave*32 + lrow)*K + lcol;
  const UST* Bg = Bt + (size_t)(bn*128 + wave*32 + lrow)*K + lcol;

  f32x4 zero = {0.f,0.f,0.f,0.f};
  f32x4 acc[4][4];
#pragma unroll
  for (int i=0;i<4;++i)
#pragma unroll
    for (int j=0;j<4;++j) acc[i][j] = zero;

  const int nkt = K >> 6;
  auto stage = [&](int kt, int buf){
#pragma unroll
    for (int c = 0; c < 4; ++c){
      __builtin_amdgcn_global_load_lds((glob_u32*)(Ag + (size_t)kt*64 + (size_t)(8*c)*K),
                                       (lds_u32*)(&lA[buf][wave*32 + 8*c][0]), 16, 0, 0);
      __builtin_amdgcn_global_load_lds((glob_u32*)(Bg + (size_t)kt*64 + (size_t)(8*c)*K),
                                       (lds_u32*)(&lB[buf][wave*32 + 8*c][0]), 16, 0, 0);
    }
  };

  stage(0, 0);
  __syncthreads();
  const int swz = (lm & 7) << 3;

  for (int kt = 0; kt < nkt; ++kt){
    const int cur = kt & 1;
    if (kt + 1 < nkt) stage(kt + 1, cur ^ 1);
#pragma unroll
    for (int ks = 0; ks < 2; ++ks){
      bf16x8 af[4], bfv[4];
      const int cb = (ks*32 + g*8) ^ swz;
#pragma unroll
      for (int mf = 0; mf < 4; ++mf)
        af[mf] = __builtin_bit_cast(bf16x8, *(const us8*)&lA[cur][wr + mf*16 + lm][cb]);
#pragma unroll
      for (int nf = 0; nf < 4; ++nf)
        bfv[nf] = __builtin_bit_cast(bf16x8, *(const us8*)&lB[cur][wc + nf*16 + lm][cb]);
#pragma unroll
      for (int mf = 0; mf < 4; ++mf)
#pragma unroll
        for (int nf = 0; nf < 4; ++nf)
          acc[mf][nf] = __builtin_amdgcn_mfma_f32_16x16x32_bf16(af[mf], bfv[nf], acc[mf][nf], 0, 0, 0);
    }
    __syncthreads();   // drains vmcnt -> next buffer ready; protects buffer reuse
  }

#pragma unroll
  for (int nf = 0; nf < 4; ++nf){
    const int col = bn*128 + wc + nf*16 + lm;     // global weight column
    const float bv = bias[col];
    if (EPI == 2){
      const int cv = col - 2816;                  // v-feature 0..1407
      const int h = cv / 88, d = cv - h*88;
#pragma unroll
      for (int mf = 0; mf < 4; ++mf){
        const int rb = bm*128 + wr + mf*16 + g*4; // global row (b*576+s)
        const int b2 = rb / 576, s = rb - b2*576; // 4-row span never crosses b
        UST* dst = (UST*)Cout + ((size_t)((b2*16 + h)*96 + d))*576 + s;
        us4 pk;
#pragma unroll
        for (int r = 0; r < 4; ++r) pk[r] = f2bf(acc[mf][nf][r] + bv);
        *(us4*)dst = pk;
      }
    } else {
#pragma unroll
      for (int mf = 0; mf < 4; ++mf){
        const size_t rb = (size_t)(bm*128 + wr + mf*16 + g*4);
#pragma unroll
        for (int r = 0; r < 4; ++r){
          float v2 = acc[mf][nf][r] + bv;
          if (EPI == 1) ((UST*)Cout)[(rb + r)*(size_t)N + col] = f2bf(v2);
          else          ((float*)Cout)[(rb + r)*(size_t)N + col] = v2;
        }
      }
    }
  }
}

// ---------------- elementwise RoPE: qkvb[9216][2816] -> qa/ka [bh][s][96] ---
// Pairs (2p,2p+1) are memory-adjacent: 8 loaded elems = 4 complete pairs,
// all in-register. cs2 = interleaved {cos,sin}, float4 = 2 pairs.
__global__ __launch_bounds__(256) void k_ropelite(
    const UST* __restrict__ qkvb, const float* __restrict__ cs2,
    UST* __restrict__ qa, UST* __restrict__ ka)
{
  int c = blockIdx.x*256 + threadIdx.x;          // 0 .. 3,244,031
  const int PER = 256*576*11;                    // chunks per j
  int j = (c >= PER);
  int c2 = c - j*PER;
  int bh = c2 / (576*11);
  int rem = c2 - bh*(576*11);
  int s = rem / 11, ch = rem - s*11;
  int b = bh >> 4, h = bh & 15;

  us8 v = *(const us8*)(qkvb + ((size_t)(b*576 + s))*2816 + j*1408 + h*88 + ch*8);
  float4 q0 = *(const float4*)(cs2 + s*88 + ch*8);      // {c,s}[p], {c,s}[p+1]
  float4 q1 = *(const float4*)(cs2 + s*88 + ch*8 + 4);  // {c,s}[p+2], {c,s}[p+3]
  const float sc = j ? 1.0f : 0.10660035817780521f;     // 88^-0.5 folded into q

  float cv[4] = {q0.x, q0.z, q1.x, q1.z};
  float sv[4] = {q0.y, q0.w, q1.y, q1.w};
  us8 o;
#pragma unroll
  for (int i = 0; i < 4; ++i){
    float x0 = bf2f(v[2*i]);
    float x1 = bf2f(v[2*i+1]);
    o[2*i]   = f2bf((x0*cv[i] - x1*sv[i])*sc);
    o[2*i+1] = f2bf((x0*sv[i] + x1*cv[i])*sc);
  }
  UST* outp = (j ? ka : qa) + ((size_t)bh*576 + s)*96;
  *(us8*)(outp + ch*8) = o;
  if (ch == 10){ us8 z = {0,0,0,0,0,0,0,0}; *(us8*)(outp + 88) = z; }  // pad
}

// ---------------- flash attention (round-2 proven): per (bh, qtile64) -------
__global__ __launch_bounds__(256, 2) void k_attn(
    const UST* __restrict__ qa, const UST* __restrict__ ka,
    const UST* __restrict__ vt, UST* __restrict__ outp)
{
  __shared__ __align__(16) UST lK[64][104];   // K tile [kv][d]
  __shared__ __align__(16) UST lV[96][72];    // V^T tile [d][kv]
  __shared__ __align__(16) UST lP[4][16][72]; // per-wave P [q][kv]
  const int bh = blockIdx.x, qt = blockIdx.y;
  const int t = threadIdx.x, wave = t >> 6, lane = t & 63;
  const int lm = lane & 15, g = lane >> 4;
  const int h = bh & 15, b = bh >> 4;

  bf16x8 qf[3];
  {
    const UST* qp = qa + ((size_t)bh*576 + qt*64 + wave*16 + lm)*96 + g*8;
#pragma unroll
    for (int ks = 0; ks < 3; ++ks) qf[ks] = __builtin_bit_cast(bf16x8, *(const us8*)(qp + ks*32));
  }
  f32x4 zero = {0.f,0.f,0.f,0.f};
  f32x4 acc[6];
#pragma unroll
  for (int i = 0; i < 6; ++i) acc[i] = zero;
  float mrun[4], lrun[4];
#pragma unroll
  for (int r = 0; r < 4; ++r){ mrun[r] = -1e30f; lrun[r] = 0.f; }

  const UST* kbase = ka + (size_t)bh*576*96;
  const UST* vbase = vt + (size_t)bh*96*576;

  for (int kvt = 0; kvt < 9; ++kvt){
    { // stage K [64][96]
      int r = t >> 2, u = t & 3;
      const UST* src = kbase + (size_t)(kvt*64 + r)*96 + u*24;
#pragma unroll
      for (int i = 0; i < 3; ++i)
        *(uint4*)&lK[r][u*24 + i*8] = *(const uint4*)(src + i*8);
    }
    if (t < 192){ // stage V^T [96][64]
      int d = t >> 1, hf = t & 1;
      const UST* src = vbase + (size_t)d*576 + kvt*64 + hf*32;
#pragma unroll
      for (int i = 0; i < 4; ++i)
        *(uint4*)&lV[d][hf*32 + i*8] = *(const uint4*)(src + i*8);
    }
    __syncthreads();

    // QK^T -> sc[nf][r]: S[q = w*16 + 4g+r][kv = nf*16 + lm]
    f32x4 sc[4];
#pragma unroll
    for (int i = 0; i < 4; ++i) sc[i] = zero;
#pragma unroll
    for (int ks = 0; ks < 3; ++ks){
#pragma unroll
      for (int nf = 0; nf < 4; ++nf){
        bf16x8 kf = __builtin_bit_cast(bf16x8, *(const us8*)&lK[nf*16 + lm][ks*32 + g*8]);
        sc[nf] = __builtin_amdgcn_mfma_f32_16x16x32_bf16(qf[ks], kf, sc[nf], 0, 0, 0);
      }
    }
    // online softmax (rows 4g+r; reduce over lm lanes + nf frags)
    float mx[4];
#pragma unroll
    for (int r = 0; r < 4; ++r)
      mx[r] = fmaxf(fmaxf(sc[0][r], sc[1][r]), fmaxf(sc[2][r], sc[3][r]));
#pragma unroll
    for (int m = 1; m <= 8; m <<= 1)
#pragma unroll
      for (int r = 0; r < 4; ++r) mx[r] = fmaxf(mx[r], __shfl_xor(mx[r], m, 64));
    float al[4];
#pragma unroll
    for (int r = 0; r < 4; ++r){
      float mnew = fmaxf(mrun[r], mx[r]);
      float corr = __expf(mrun[r] - mnew);
      mrun[r] = mnew;
      lrun[r] *= corr;
      float ls = 0.f;
#pragma unroll
      for (int nf = 0; nf < 4; ++nf){
        float p = __expf(sc[nf][r] - mnew);
        sc[nf][r] = p;
        ls += p;
      }
#pragma unroll
      for (int df = 0; df < 6; ++df) acc[df][r] *= corr;
      al[r] = ls;
    }
#pragma unroll
    for (int m = 1; m <= 8; m <<= 1)
#pragma unroll
      for (int r = 0; r < 4; ++r) al[r] += __shfl_xor(al[r], m, 64);
#pragma unroll
    for (int r = 0; r < 4; ++r) lrun[r] += al[r];

    // P -> LDS (wave-local), read back as A-frags
#pragma unroll
    for (int nf = 0; nf < 4; ++nf)
#pragma unroll
      for (int r = 0; r < 4; ++r)
        lP[wave][4*g + r][nf*16 + lm] = f2bf(sc[nf][r]);

    bf16x8 pa[2];
#pragma unroll
    for (int ks2 = 0; ks2 < 2; ++ks2)
      pa[ks2] = __builtin_bit_cast(bf16x8, *(const us8*)&lP[wave][lm][ks2*32 + g*8]);
#pragma unroll
    for (int ks2 = 0; ks2 < 2; ++ks2)
#pragma unroll
      for (int df = 0; df < 6; ++df){
        bf16x8 vf = __builtin_bit_cast(bf16x8, *(const us8*)&lV[df*16 + lm][ks2*32 + g*8]);
        acc[df] = __builtin_amdgcn_mfma_f32_16x16x32_bf16(pa[ks2], vf, acc[df], 0, 0, 0);
      }
    __syncthreads();
  }

  float inv[4];
#pragma unroll
  for (int r = 0; r < 4; ++r) inv[r] = 1.f / lrun[r];
  const size_t rowt = (size_t)b*576 + qt*64 + wave*16;
#pragma unroll
  for (int df = 0; df < 6; ++df){
    int d = df*16 + lm;
    if (d < 88){
#pragma unroll
      for (int r = 0; r < 4; ++r)
        outp[(rowt + 4*g + r)*1408 + h*88 + d] = f2bf(acc[df][r] * inv[r]);
    }
  }
}

// ---------------- launch ----------------------------------------------------
extern "C" void kernel_launch(void* const* d_in, const int* in_sizes, int n_in,
                              void* d_out, int out_size, void* d_ws, size_t ws_size,
                              hipStream_t stream)
{
  (void)in_sizes; (void)n_in; (void)out_size; (void)ws_size;
  const float* hs   = (const float*)d_in[0];
  const float* wqkv = (const float*)d_in[1];
  const float* bqkv = (const float*)d_in[2];
  const float* wo   = (const float*)d_in[3];
  const float* bo   = (const float*)d_in[4];
  float* out = (float*)d_out;

  char* w = (char*)d_ws;                       // needs ~179 MiB
  UST* A_bf   = (UST*)(w);                     // 25,952,256  (hidden bf16; reused as attn out)
  UST* Bt1    = (UST*)(w + 25952256);          // 11,894,784  (w_qkv^T bf16)
  UST* Bt2    = (UST*)(w + 37847040);          //  3,964,928  (w_o^T bf16)
  UST* qkvb   = (UST*)(w + 41811968);          // 51,904,512  (qk only, [9216][2816])
  UST* qa     = (UST*)(w + 93716480);          // 28,311,552
  UST* ka     = (UST*)(w + 122028032);         // 28,311,552
  UST* vt     = (UST*)(w + 150339584);         // 28,311,552
  float* cs2  = (float*)(w + 178651136);       //    202,752

  k_tables<<<576, 64, 0, stream>>>(cs2);
  k_zero<<<576, 256, 0, stream>>>(vt);
  k_cvt<<<12672, 256, 0, stream>>>(hs, A_bf, 3244032);
  k_cvt_t<<<dim3(22, 66), 256, 0, stream>>>(wqkv, Bt1, 1408, 4224);
  k_cvt_t<<<dim3(22, 22), 256, 0, stream>>>(wo, Bt2, 1408, 1408);
  k_gemm<1><<<dim3(72, 22), 256, 0, stream>>>(A_bf, Bt1, bqkv, qkvb, 9216, 2816, 1408, 0);
  k_gemm<2><<<dim3(72, 11), 256, 0, stream>>>(A_bf, Bt1, bqkv, vt,   9216, 0,    1408, 22);
  k_ropelite<<<12672, 256, 0, stream>>>(qkvb, cs2, qa, ka);
  k_attn<<<dim3(256, 9), 256, 0, stream>>>(qa, ka, vt, A_bf);
  k_gemm<0><<<dim3(72, 11), 256, 0, stream>>>(A_bf, Bt2, bo, out, 9216, 1408, 1408, 0);
}

// Round 6
// 330.019 us; speedup vs baseline: 1.1708x; 1.0893x over previous
//
#include <hip/hip_runtime.h>
#include <hip/hip_bf16.h>

// Llama4 Vision Attention, MI355X bf16-MFMA pipeline.
// B=16 S=576 E=1408 H=16 D=88 (pad 96). fp32 in/out, bf16 internal compute.
// R6: single QKV GEMM with 3-way fused epilogue (q/k: in-register rope via
//     lane-pair shfl + feature-major cos/sin tables; v: transposed store).
//     qkvb buffer and rope pass fully eliminated.

typedef unsigned short UST;
typedef __attribute__((ext_vector_type(8))) __bf16 bf16x8;
typedef __attribute__((ext_vector_type(4))) float f32x4;
typedef __attribute__((ext_vector_type(8))) UST us8;
typedef __attribute__((ext_vector_type(4))) UST us4;

typedef __attribute__((address_space(3))) unsigned int lds_u32;
typedef const __attribute__((address_space(1))) unsigned int glob_u32;

static __device__ __forceinline__ float bf2f(UST u){
  unsigned int x = ((unsigned int)u) << 16;
  return __builtin_bit_cast(float, x);
}
static __device__ __forceinline__ UST f2bf(float f){
  unsigned int x = __builtin_bit_cast(unsigned int, f);
  x += 0x7fffu + ((x >> 16) & 1u);   // RN-even; inputs finite
  return (UST)(x >> 16);
}

// ------ RoPE tables, feature-major: cosT/sinT[88][576]; d and d^1 share p=d>>1
__global__ void k_tables(float* __restrict__ cosT, float* __restrict__ sinT){
  int s = blockIdx.x;
  int d = threadIdx.x;
  if (d >= 88) return;
  int p = d >> 1;
  int tt = p % 22;
  double comp = (p < 22) ? (double)(s % 24 + 1) : (double)(s / 24 + 1);
  double a = comp * pow(10000.0, -(double)tt / 22.0);
  cosT[d*576 + s] = (float)cos(a);
  sinT[d*576 + s] = (float)sin(a);
}

// ------ zero pads: qa/ka cols 88..95 per row; vt rows d=88..95 --------------
__global__ void k_zero(UST* __restrict__ qa, UST* __restrict__ ka, UST* __restrict__ vt){
  int c = blockIdx.x*256 + threadIdx.x;        // 0..147455 = 256bh * 576
  int bh = c / 576, s = c - bh*576;
  us8 z = {0,0,0,0,0,0,0,0};
  *(us8*)(qa + ((size_t)bh*576 + s)*96 + 88) = z;
  *(us8*)(ka + ((size_t)bh*576 + s)*96 + 88) = z;
  *(us8*)(vt + (size_t)bh*55296 + 50688 + s*8) = z;   // rows 88..95 of [96][576]
}

// ---------------- fp32 -> bf16 cast (vectorized) ----------------------------
__global__ void k_cvt(const float* __restrict__ in, UST* __restrict__ out, int n4){
  int i = blockIdx.x * 256 + threadIdx.x;
  if (i >= n4) return;
  float4 v = ((const float4*)in)[i];
  us4 o; o[0]=f2bf(v.x); o[1]=f2bf(v.y); o[2]=f2bf(v.z); o[3]=f2bf(v.w);
  *(us4*)(out + 4*(size_t)i) = o;
}

// ---------------- fp32 [K][N] -> bf16 [N][K] transpose-convert --------------
__global__ void k_cvt_t(const float* __restrict__ W, UST* __restrict__ Bt, int K, int N){
  __shared__ __align__(16) UST tl[64][70];  // odd dword stride -> low conflict
  int kt = blockIdx.x, nt = blockIdx.y;
  int t = threadIdx.x;
  int k = t >> 2, u = t & 3;
  const float* src = W + (size_t)(kt*64 + k)*N + nt*64 + u*16;
#pragma unroll
  for (int i = 0; i < 4; ++i){
    float4 v = *(const float4*)(src + 4*i);
    UST* d = &tl[k][u*16 + 4*i];
    d[0]=f2bf(v.x); d[1]=f2bf(v.y); d[2]=f2bf(v.z); d[3]=f2bf(v.w);
  }
  __syncthreads();
  int n = t >> 2;
  UST* dst = Bt + (size_t)(nt*64 + n)*K + kt*64 + u*16;
#pragma unroll
  for (int i = 0; i < 2; ++i){
    us8 o;
#pragma unroll
    for (int j = 0; j < 8; ++j) o[j] = tl[u*16 + 8*i + j][n];
    *(us8*)(dst + 8*i) = o;
  }
}

// ---------------- bf16 GEMM (round-2 proven body) + fused epilogues ---------
// EPI 0: fp32 out, stride N (final projection).
// EPI 3: QKV fused — region j = bn/11 uniform per block (1408 = 11*128):
//   j=0/1 (q/k): bias + rope in-register (pair partner = lane^1 via shfl;
//                col parity == lm parity; pairs never cross h since 88 even),
//                q scaled by 88^-0.5, store bf16 -> qa/ka [bh][s][96].
//   j=2   (v):   bias + transpose-store bf16 -> vt [bh][96][576].
template<int EPI>
__global__ __launch_bounds__(256, 2) void k_gemm(
    const UST* __restrict__ A, const UST* __restrict__ Bt,
    const float* __restrict__ bias, void* __restrict__ Cout,
    int M, int N, int K,
    UST* __restrict__ qa, UST* __restrict__ ka, UST* __restrict__ vt,
    const float* __restrict__ cosT, const float* __restrict__ sinT)
{
  __shared__ __align__(16) UST lA[2][128][64];
  __shared__ __align__(16) UST lB[2][128][64];
  const int t = threadIdx.x;
  const int bm = blockIdx.x, bn = blockIdx.y;
  const int wave = t >> 6, lane = t & 63;
  const int lm = lane & 15, g = lane >> 4;
  const int wr = (wave >> 1) << 6, wc = (wave & 1) << 6;
  const int lrow = lane >> 3;                       // 0..7 within 8-row chunk
  const int lcol = (((lane & 7) ^ lrow) << 3);      // pre-swizzled source col
  const UST* Ag = A  + (size_t)(bm*128 + wave*32 + lrow)*K + lcol;
  const UST* Bg = Bt + (size_t)(bn*128 + wave*32 + lrow)*K + lcol;

  f32x4 zero = {0.f,0.f,0.f,0.f};
  f32x4 acc[4][4];
#pragma unroll
  for (int i=0;i<4;++i)
#pragma unroll
    for (int j=0;j<4;++j) acc[i][j] = zero;

  const int nkt = K >> 6;
  auto stage = [&](int kt, int buf){
#pragma unroll
    for (int c = 0; c < 4; ++c){
      __builtin_amdgcn_global_load_lds((glob_u32*)(Ag + (size_t)kt*64 + (size_t)(8*c)*K),
                                       (lds_u32*)(&lA[buf][wave*32 + 8*c][0]), 16, 0, 0);
      __builtin_amdgcn_global_load_lds((glob_u32*)(Bg + (size_t)kt*64 + (size_t)(8*c)*K),
                                       (lds_u32*)(&lB[buf][wave*32 + 8*c][0]), 16, 0, 0);
    }
  };

  stage(0, 0);
  __syncthreads();
  const int swz = (lm & 7) << 3;

  for (int kt = 0; kt < nkt; ++kt){
    const int cur = kt & 1;
    if (kt + 1 < nkt) stage(kt + 1, cur ^ 1);
#pragma unroll
    for (int ks = 0; ks < 2; ++ks){
      bf16x8 af[4], bfv[4];
      const int cb = (ks*32 + g*8) ^ swz;
#pragma unroll
      for (int mf = 0; mf < 4; ++mf)
        af[mf] = __builtin_bit_cast(bf16x8, *(const us8*)&lA[cur][wr + mf*16 + lm][cb]);
#pragma unroll
      for (int nf = 0; nf < 4; ++nf)
        bfv[nf] = __builtin_bit_cast(bf16x8, *(const us8*)&lB[cur][wc + nf*16 + lm][cb]);
#pragma unroll
      for (int mf = 0; mf < 4; ++mf)
#pragma unroll
        for (int nf = 0; nf < 4; ++nf)
          acc[mf][nf] = __builtin_amdgcn_mfma_f32_16x16x32_bf16(af[mf], bfv[nf], acc[mf][nf], 0, 0, 0);
    }
    __syncthreads();   // drains vmcnt -> next buffer ready; protects buffer reuse
  }

  if (EPI == 0){
#pragma unroll
    for (int nf = 0; nf < 4; ++nf){
      const int col = bn*128 + wc + nf*16 + lm;
      const float bv = bias[col];
#pragma unroll
      for (int mf = 0; mf < 4; ++mf){
        const size_t rb = (size_t)(bm*128 + wr + mf*16 + g*4);
#pragma unroll
        for (int r = 0; r < 4; ++r)
          ((float*)Cout)[(rb + r)*(size_t)N + col] = acc[mf][nf][r] + bv;
      }
    }
  } else {
    const int j = bn / 11;               // 0 q, 1 k, 2 v (uniform per block)
    const int bnr = bn - j*11;
    if (j == 2){
#pragma unroll
      for (int nf = 0; nf < 4; ++nf){
        const int cv = bnr*128 + wc + nf*16 + lm;   // v-feature 0..1407
        const float bv = bias[2816 + cv];
        const int h = cv / 88, d = cv - h*88;
#pragma unroll
        for (int mf = 0; mf < 4; ++mf){
          const int rb = bm*128 + wr + mf*16 + g*4; // global row (b*576+s)
          const int b2 = rb / 576, s = rb - b2*576; // 4-row span never crosses b
          UST* dst = vt + ((size_t)((b2*16 + h)*96 + d))*576 + s;
          us4 pk;
#pragma unroll
          for (int r = 0; r < 4; ++r) pk[r] = f2bf(acc[mf][nf][r] + bv);
          *(us4*)dst = pk;
        }
      }
    } else {
      UST* outp = j ? ka : qa;
      const float sc = j ? 1.0f : 0.10660035817780521f;   // 88^-0.5 into q
      const bool even = (lm & 1) == 0;
#pragma unroll
      for (int nf = 0; nf < 4; ++nf){
        const int cv = bnr*128 + wc + nf*16 + lm;   // q/k feature 0..1407
        const float bv = bias[j*1408 + cv];
        const int h = cv / 88, d = cv - h*88;
        const float* cT = cosT + d*576;
        const float* sT = sinT + d*576;
#pragma unroll
        for (int mf = 0; mf < 4; ++mf){
          const int rb = bm*128 + wr + mf*16 + g*4;
          const int b2 = rb / 576, s = rb - b2*576;
          float4 c4 = *(const float4*)(cT + s);
          float4 s4 = *(const float4*)(sT + s);
          float cc[4] = {c4.x, c4.y, c4.z, c4.w};
          float ss[4] = {s4.x, s4.y, s4.z, s4.w};
          UST* dst = outp + ((size_t)(b2*16 + h)*576 + s)*96 + d;
#pragma unroll
          for (int r = 0; r < 4; ++r){
            float vs = acc[mf][nf][r] + bv;         // own column value
            float vo = __shfl_xor(vs, 1, 64);       // partner column (lane^1)
            float o = even ? (vs*cc[r] - vo*ss[r])  // x0*c - x1*s
                           : (vo*ss[r] + vs*cc[r]); // x0*s + x1*c
            dst[(size_t)r*96] = f2bf(o * sc);
          }
        }
      }
    }
  }
}

// ---------------- flash attention (round-2 proven): per (bh, qtile64) -------
__global__ __launch_bounds__(256, 2) void k_attn(
    const UST* __restrict__ qa, const UST* __restrict__ ka,
    const UST* __restrict__ vt, UST* __restrict__ outp)
{
  __shared__ __align__(16) UST lK[64][104];   // K tile [kv][d]
  __shared__ __align__(16) UST lV[96][72];    // V^T tile [d][kv]
  __shared__ __align__(16) UST lP[4][16][72]; // per-wave P [q][kv]
  const int bh = blockIdx.x, qt = blockIdx.y;
  const int t = threadIdx.x, wave = t >> 6, lane = t & 63;
  const int lm = lane & 15, g = lane >> 4;
  const int h = bh & 15, b = bh >> 4;

  bf16x8 qf[3];
  {
    const UST* qp = qa + ((size_t)bh*576 + qt*64 + wave*16 + lm)*96 + g*8;
#pragma unroll
    for (int ks = 0; ks < 3; ++ks) qf[ks] = __builtin_bit_cast(bf16x8, *(const us8*)(qp + ks*32));
  }
  f32x4 zero = {0.f,0.f,0.f,0.f};
  f32x4 acc[6];
#pragma unroll
  for (int i = 0; i < 6; ++i) acc[i] = zero;
  float mrun[4], lrun[4];
#pragma unroll
  for (int r = 0; r < 4; ++r){ mrun[r] = -1e30f; lrun[r] = 0.f; }

  const UST* kbase = ka + (size_t)bh*576*96;
  const UST* vbase = vt + (size_t)bh*96*576;

  for (int kvt = 0; kvt < 9; ++kvt){
    { // stage K [64][96]
      int r = t >> 2, u = t & 3;
      const UST* src = kbase + (size_t)(kvt*64 + r)*96 + u*24;
#pragma unroll
      for (int i = 0; i < 3; ++i)
        *(uint4*)&lK[r][u*24 + i*8] = *(const uint4*)(src + i*8);
    }
    if (t < 192){ // stage V^T [96][64]
      int d = t >> 1, hf = t & 1;
      const UST* src = vbase + (size_t)d*576 + kvt*64 + hf*32;
#pragma unroll
      for (int i = 0; i < 4; ++i)
        *(uint4*)&lV[d][hf*32 + i*8] = *(const uint4*)(src + i*8);
    }
    __syncthreads();

    // QK^T -> sc[nf][r]: S[q = w*16 + 4g+r][kv = nf*16 + lm]
    f32x4 sc[4];
#pragma unroll
    for (int i = 0; i < 4; ++i) sc[i] = zero;
#pragma unroll
    for (int ks = 0; ks < 3; ++ks){
#pragma unroll
      for (int nf = 0; nf < 4; ++nf){
        bf16x8 kf = __builtin_bit_cast(bf16x8, *(const us8*)&lK[nf*16 + lm][ks*32 + g*8]);
        sc[nf] = __builtin_amdgcn_mfma_f32_16x16x32_bf16(qf[ks], kf, sc[nf], 0, 0, 0);
      }
    }
    // online softmax (rows 4g+r; reduce over lm lanes + nf frags)
    float mx[4];
#pragma unroll
    for (int r = 0; r < 4; ++r)
      mx[r] = fmaxf(fmaxf(sc[0][r], sc[1][r]), fmaxf(sc[2][r], sc[3][r]));
#pragma unroll
    for (int m = 1; m <= 8; m <<= 1)
#pragma unroll
      for (int r = 0; r < 4; ++r) mx[r] = fmaxf(mx[r], __shfl_xor(mx[r], m, 64));
    float al[4];
#pragma unroll
    for (int r = 0; r < 4; ++r){
      float mnew = fmaxf(mrun[r], mx[r]);
      float corr = __expf(mrun[r] - mnew);
      mrun[r] = mnew;
      lrun[r] *= corr;
      float ls = 0.f;
#pragma unroll
      for (int nf = 0; nf < 4; ++nf){
        float p = __expf(sc[nf][r] - mnew);
        sc[nf][r] = p;
        ls += p;
      }
#pragma unroll
      for (int df = 0; df < 6; ++df) acc[df][r] *= corr;
      al[r] = ls;
    }
#pragma unroll
    for (int m = 1; m <= 8; m <<= 1)
#pragma unroll
      for (int r = 0; r < 4; ++r) al[r] += __shfl_xor(al[r], m, 64);
#pragma unroll
    for (int r = 0; r < 4; ++r) lrun[r] += al[r];

    // P -> LDS (wave-local), read back as A-frags
#pragma unroll
    for (int nf = 0; nf < 4; ++nf)
#pragma unroll
      for (int r = 0; r < 4; ++r)
        lP[wave][4*g + r][nf*16 + lm] = f2bf(sc[nf][r]);

    bf16x8 pa[2];
#pragma unroll
    for (int ks2 = 0; ks2 < 2; ++ks2)
      pa[ks2] = __builtin_bit_cast(bf16x8, *(const us8*)&lP[wave][lm][ks2*32 + g*8]);
#pragma unroll
    for (int ks2 = 0; ks2 < 2; ++ks2)
#pragma unroll
      for (int df = 0; df < 6; ++df){
        bf16x8 vf = __builtin_bit_cast(bf16x8, *(const us8*)&lV[df*16 + lm][ks2*32 + g*8]);
        acc[df] = __builtin_amdgcn_mfma_f32_16x16x32_bf16(pa[ks2], vf, acc[df], 0, 0, 0);
      }
    __syncthreads();
  }

  float inv[4];
#pragma unroll
  for (int r = 0; r < 4; ++r) inv[r] = 1.f / lrun[r];
  const size_t rowt = (size_t)b*576 + qt*64 + wave*16;
#pragma unroll
  for (int df = 0; df < 6; ++df){
    int d = df*16 + lm;
    if (d < 88){
#pragma unroll
      for (int r = 0; r < 4; ++r)
        outp[(rowt + 4*g + r)*1408 + h*88 + d] = f2bf(acc[df][r] * inv[r]);
    }
  }
}

// ---------------- launch ----------------------------------------------------
extern "C" void kernel_launch(void* const* d_in, const int* in_sizes, int n_in,
                              void* d_out, int out_size, void* d_ws, size_t ws_size,
                              hipStream_t stream)
{
  (void)in_sizes; (void)n_in; (void)out_size; (void)ws_size;
  const float* hs   = (const float*)d_in[0];
  const float* wqkv = (const float*)d_in[1];
  const float* bqkv = (const float*)d_in[2];
  const float* wo   = (const float*)d_in[3];
  const float* bo   = (const float*)d_in[4];
  float* out = (float*)d_out;

  char* w = (char*)d_ws;                       // needs ~127.5 MiB
  UST* A_bf   = (UST*)(w);                     // 25,952,256  (hidden bf16; reused as attn out)
  UST* Bt1    = (UST*)(w + 25952256);          // 11,894,784  (w_qkv^T bf16)
  UST* Bt2    = (UST*)(w + 37847040);          //  3,964,928  (w_o^T bf16)
  UST* qa     = (UST*)(w + 41811968);          // 28,311,552
  UST* ka     = (UST*)(w + 70123520);          // 28,311,552
  UST* vt     = (UST*)(w + 98435072);          // 28,311,552
  float* cosT = (float*)(w + 126746624);       //    202,752
  float* sinT = (float*)(w + 126949376);       //    202,752

  k_tables<<<576, 128, 0, stream>>>(cosT, sinT);
  k_zero<<<576, 256, 0, stream>>>(qa, ka, vt);
  k_cvt<<<12672, 256, 0, stream>>>(hs, A_bf, 3244032);
  k_cvt_t<<<dim3(22, 66), 256, 0, stream>>>(wqkv, Bt1, 1408, 4224);
  k_cvt_t<<<dim3(22, 22), 256, 0, stream>>>(wo, Bt2, 1408, 1408);
  k_gemm<3><<<dim3(72, 33), 256, 0, stream>>>(A_bf, Bt1, bqkv, nullptr, 9216, 4224, 1408,
                                              qa, ka, vt, cosT, sinT);
  k_attn<<<dim3(256, 9), 256, 0, stream>>>(qa, ka, vt, A_bf);
  k_gemm<0><<<dim3(72, 11), 256, 0, stream>>>(A_bf, Bt2, bo, out, 9216, 1408, 1408,
                                              nullptr, nullptr, nullptr, nullptr, nullptr);
}